// Round 5
// baseline (34.278 us; speedup 1.0000x reference)
//
#include <hip/hip_runtime.h>
#include <math.h>

#define BATCH 8
#define LEN   2048
#define FEAT  8
#define IR    4                     // pred rows register-tiled per lane
#define WAVES 4
#define THREADS (WAVES * 64)        // 256
#define ROWS  (WAVES * IR)          // 16 pred rows per block
#define CHUNK 1024                  // target rows staged per phase (36 KB LDS)
#define KSTEPS (CHUNK / 64)         // 16 j-iterations per lane per phase
#define NBLK  (BATCH * (LEN / ROWS))  // 1024 blocks = 4/CU
#define PARTIAL_OFF 64              // float offset of partials in d_ws
#define LOG2E 1.4426950408889634f
#define LN2   0.6931471805599453f

typedef float v2f __attribute__((ext_vector_type(2)));

__device__ __forceinline__ v2f pk_mul(v2f a, v2f b) {
    v2f d; asm("v_pk_mul_f32 %0, %1, %2" : "=v"(d) : "v"(a), "v"(b)); return d;
}
__device__ __forceinline__ v2f pk_fma(v2f a, v2f b, v2f c) {
    v2f d; asm("v_pk_fma_f32 %0, %1, %2, %3" : "=v"(d) : "v"(a), "v"(b), "v"(c)); return d;
}

#if __has_builtin(__builtin_amdgcn_exp2f)
#define EXP2F(x) __builtin_amdgcn_exp2f(x)
#else
#define EXP2F(x) exp2f(x)
#endif
#if __has_builtin(__builtin_amdgcn_logf)
#define LOG2FH(x) __builtin_amdgcn_logf(x)   // hardware log2
#else
#define LOG2FH(x) log2f(x)
#endif

// Single fused kernel. Per block: 16 pred rows (4 waves x 4 rows-in-regs),
// all 2048 targets via two 1024-row LDS phases. Scaling folded into pred:
//   pr = (2*log2e)*p, mp2 = -log2e*||p||^2, s_mt2 = -log2e*||t||^2, s_t = t.
//   x = pr.t + mp2 + mt2 = -log2e*dist; exp2(x) = exp(-dist).
// LDS granule swizzle g = 2j + ((j>>2)&1): every bank serves exactly 8 words
// per wave b128 access (balanced = throughput-optimal).
// T14 stage split: phase-1 global loads are issued before phase-0 compute so
// their latency hides under it; ds_write lands after the phase-0 barrier.
// Final reduction: rocPRIM last-block pattern (agent-scope ACQ_REL counter in
// ws[0], partials at ws[PARTIAL_OFF]) -> one launch, bitwise-deterministic.
__global__ __launch_bounds__(THREADS, 4) void dtw_fused(
    const float* __restrict__ pred, const float* __restrict__ target,
    float* __restrict__ ws, float* __restrict__ out)
{
    __shared__ float4 s_t[CHUNK * 2];   // swizzled target rows, 32 KB
    __shared__ float  s_mt2[CHUNK];     // -log2e*||t||^2, 4 KB
    __shared__ float  s_wsum[WAVES];
    __shared__ int    s_last;

    const int tid = threadIdx.x;
    const int b   = blockIdx.x / (LEN / ROWS);
    const int rb  = blockIdx.x % (LEN / ROWS);
    const int w   = tid >> 6;           // wave = row-group
    const int ln  = tid & 63;           // j-lane within wave
    const int i0  = rb * ROWS + w * IR;

    // ---- this wave's 4 pred rows -> registers, pre-scaled by 2*log2e ----
    const float4* p4 = (const float4*)(pred + ((size_t)b * LEN + i0) * FEAT);
    v2f  pr[IR][4];
    float mp2[IR];
    #pragma unroll
    for (int r = 0; r < IR; ++r) {
        float4 a = p4[r * 2];
        float4 c = p4[r * 2 + 1];
        const float s2 = 2.f * LOG2E;
        pr[r][0] = (v2f){a.x * s2, a.y * s2};
        pr[r][1] = (v2f){a.z * s2, a.w * s2};
        pr[r][2] = (v2f){c.x * s2, c.y * s2};
        pr[r][3] = (v2f){c.z * s2, c.w * s2};
        mp2[r] = -LOG2E * (a.x*a.x + a.y*a.y + a.z*a.z + a.w*a.w
                         + c.x*c.x + c.y*c.y + c.z*c.z + c.w*c.w);
    }

    const float4* t4 = (const float4*)(target + (size_t)b * LEN * FEAT);
    float acc[IR];
    #pragma unroll
    for (int r = 0; r < IR; ++r) acc[r] = 0.f;

    // ---- phase-0 stage: load -> LDS (short register liveness) ----
    #pragma unroll
    for (int u = 0; u < CHUNK / THREADS; ++u) {
        const int jj = u * THREADS + tid;
        float4 ta = t4[(size_t)jj * 2];
        float4 tb = t4[(size_t)jj * 2 + 1];
        float t2 = ta.x*ta.x + ta.y*ta.y + ta.z*ta.z + ta.w*ta.w
                 + tb.x*tb.x + tb.y*tb.y + tb.z*tb.z + tb.w*tb.w;
        const int g = 2 * jj + ((jj >> 2) & 1);
        s_t[g]     = ta;
        s_t[g ^ 1] = tb;
        s_mt2[jj]  = -LOG2E * t2;
    }
    __syncthreads();

    // ---- issue phase-1 global loads NOW; latency hides under compute-0 ----
    float4 g1a[CHUNK / THREADS], g1b[CHUNK / THREADS];
    #pragma unroll
    for (int u = 0; u < CHUNK / THREADS; ++u) {
        const int jj = CHUNK + u * THREADS + tid;
        g1a[u] = t4[(size_t)jj * 2];
        g1b[u] = t4[(size_t)jj * 2 + 1];
    }

    // ---- compute phase 0 ----
    #pragma unroll 4
    for (int k = 0; k < KSTEPS; ++k) {
        const int jj = k * 64 + ln;
        const int g  = 2 * jj + ((jj >> 2) & 1);
        float4 ta = s_t[g];
        float4 tb = s_t[g ^ 1];
        float mt2 = s_mt2[jj];
        v2f t01 = (v2f){ta.x, ta.y};
        v2f t23 = (v2f){ta.z, ta.w};
        v2f t45 = (v2f){tb.x, tb.y};
        v2f t67 = (v2f){tb.z, tb.w};
        #pragma unroll
        for (int r = 0; r < IR; ++r) {
            v2f a2 = pk_mul(t01, pr[r][0]);
            a2 = pk_fma(t23, pr[r][1], a2);
            a2 = pk_fma(t45, pr[r][2], a2);
            a2 = pk_fma(t67, pr[r][3], a2);
            float x = (a2.x + a2.y) + (mp2[r] + mt2);
            acc[r] += EXP2F(x);          // = exp(-dist)
        }
    }
    __syncthreads();   // all phase-0 reads done before overwrite

    // ---- stage phase 1 from held registers ----
    #pragma unroll
    for (int u = 0; u < CHUNK / THREADS; ++u) {
        const int jj = u * THREADS + tid;      // LDS-local index
        float4 ta = g1a[u];
        float4 tb = g1b[u];
        float t2 = ta.x*ta.x + ta.y*ta.y + ta.z*ta.z + ta.w*ta.w
                 + tb.x*tb.x + tb.y*tb.y + tb.z*tb.z + tb.w*tb.w;
        const int g = 2 * jj + ((jj >> 2) & 1);
        s_t[g]     = ta;
        s_t[g ^ 1] = tb;
        s_mt2[jj]  = -LOG2E * t2;
    }
    __syncthreads();

    // ---- compute phase 1 ----
    #pragma unroll 4
    for (int k = 0; k < KSTEPS; ++k) {
        const int jj = k * 64 + ln;
        const int g  = 2 * jj + ((jj >> 2) & 1);
        float4 ta = s_t[g];
        float4 tb = s_t[g ^ 1];
        float mt2 = s_mt2[jj];
        v2f t01 = (v2f){ta.x, ta.y};
        v2f t23 = (v2f){ta.z, ta.w};
        v2f t45 = (v2f){tb.x, tb.y};
        v2f t67 = (v2f){tb.z, tb.w};
        #pragma unroll
        for (int r = 0; r < IR; ++r) {
            v2f a2 = pk_mul(t01, pr[r][0]);
            a2 = pk_fma(t23, pr[r][1], a2);
            a2 = pk_fma(t45, pr[r][2], a2);
            a2 = pk_fma(t67, pr[r][3], a2);
            float x = (a2.x + a2.y) + (mp2[r] + mt2);
            acc[r] += EXP2F(x);
        }
    }

    // ---- per-row totals across the wave's 64 j-lanes, then soft-min ----
    float vt = 0.f;
    #pragma unroll
    for (int r = 0; r < IR; ++r) {
        float s = acc[r];
        s += __shfl_xor(s, 1);
        s += __shfl_xor(s, 2);
        s += __shfl_xor(s, 4);
        s += __shfl_xor(s, 8);
        s += __shfl_xor(s, 16);
        s += __shfl_xor(s, 32);
        vt += LOG2FH(s);                 // log2(sum exp(-d))
    }
    vt *= -LN2;                          // sum over this wave's 4 rows
    if (ln == 0) s_wsum[w] = vt;
    __syncthreads();

    // ---- last-block reduction (rocPRIM pattern) ----
    if (tid == 0) {
        float tot = s_wsum[0] + s_wsum[1] + s_wsum[2] + s_wsum[3];
        ws[PARTIAL_OFF + blockIdx.x] = tot;
        unsigned old = __hip_atomic_fetch_add(
            (unsigned*)ws, 1u, __ATOMIC_ACQ_REL, __HIP_MEMORY_SCOPE_AGENT);
        s_last = (old == NBLK - 1);
    }
    __syncthreads();
    if (s_last) {
        const volatile float* p = ws + PARTIAL_OFF;
        float v = 0.f;
        #pragma unroll
        for (int u = 0; u < NBLK / THREADS; ++u)
            v += p[u * THREADS + tid];
        v += __shfl_xor(v, 1);
        v += __shfl_xor(v, 2);
        v += __shfl_xor(v, 4);
        v += __shfl_xor(v, 8);
        v += __shfl_xor(v, 16);
        v += __shfl_xor(v, 32);
        if ((tid & 63) == 0) s_wsum[tid >> 6] = v;
        __syncthreads();
        if (tid == 0)
            out[0] = (s_wsum[0] + s_wsum[1] + s_wsum[2] + s_wsum[3])
                   * (1.0f / (BATCH * LEN));
    }
}

extern "C" void kernel_launch(void* const* d_in, const int* in_sizes, int n_in,
                              void* d_out, int out_size, void* d_ws, size_t ws_size,
                              hipStream_t stream) {
    const float* pred   = (const float*)d_in[0];
    const float* target = (const float*)d_in[1];
    float* out = (float*)d_out;
    float* ws  = (float*)d_ws;

    // zero the finished-block counter (ws[0]); partials need no init
    hipMemsetAsync(d_ws, 0, 4, stream);
    dtw_fused<<<NBLK, THREADS, 0, stream>>>(pred, target, ws, out);
}